// Round 5
// baseline (58.985 us; speedup 1.0000x reference)
//
#include <hip/hip_runtime.h>

#define BATCH   4096
#define NCTX    8
#define NK      6
#define VDIM    256
#define NWORDS  50000
#define NPAIRS  (BATCH * NK)                 // 24576
#define CBLK    32                           // O columns per tile
#define NTILES  ((NWORDS + CBLK - 1) / CBLK) // 1563
#define GRID    782                          // 2 tiles per block (782*2 = 1564 >= 1563)
#define CAP     64                           // pairs per tile list (mean 15.7, 12 sigma)

// ---------------------------------------------------------------------------
// Single fused kernel. Block bid owns O column tiles bid and bid+GRID.
// Per tile: stream 256x32 O-tile into LDS (transposed [c][t]); for each
// (b,k) pair whose target lands in the tile, one wave recomputes
// x[b] = D[doc[b]] + sum_c W[ctx[b,c]] (9 coalesced 1KB row gathers, float4
// per lane) and dots it against the LDS column. Tile-1 is register-prefetched
// during tile-0's pair phase.
// ---------------------------------------------------------------------------
__global__ __launch_bounds__(256, 4)
void DM_42417097016803_fused(const int* __restrict__ ctx,
                             const int* __restrict__ doc,
                             const int* __restrict__ tgt,
                             const float* __restrict__ D,
                             const float* __restrict__ W,
                             const float* __restrict__ O,
                             float* __restrict__ out)
{
    __shared__ float tile[CBLK][VDIM + 4];   // 33.3 KB, stride 260 floats
    __shared__ int   lst[2][CAP];
    __shared__ int   cnt[2];

    const int tid = threadIdx.x;
    const int bid = blockIdx.x;
    const int c0  = bid * CBLK;              // tile 0: always full 32 cols (c0 < 25024)
    const int c1  = (bid + GRID) * CBLK;     // tile 1: may be partial/empty
    const int n1  = NWORDS - c1;             // valid cols in tile 1 (<=0 -> empty)

    if (tid < 2) cnt[tid] = 0;
    __syncthreads();

    const int c4  = tid & 7;                 // float4-column within tile
    const int row = tid >> 3;                // 0..31

    // --- issue tile-0 loads into registers (latency overlaps the scan) ---
    float4 t0r[8];
#pragma unroll
    for (int rb = 0; rb < 8; ++rb)
        t0r[rb] = *reinterpret_cast<const float4*>(
            &O[(size_t)(rb * 32 + row) * NWORDS + c0 + c4 * 4]);

    // --- scan target ids, filter to my two column ranges ---
    const int4* __restrict__ t4 = reinterpret_cast<const int4*>(tgt);
    for (int j = tid; j < NPAIRS / 4; j += 256) {
        const int4 v = t4[j];
        const int ii = j * 4;
#define DM_CHK(cv, idx)                                                        \
        {   const unsigned d0 = (unsigned)((cv) - c0);                         \
            if (d0 < CBLK) { int s = atomicAdd(&cnt[0], 1);                    \
                             if (s < CAP) lst[0][s] = ((idx) << 5) | (int)d0; }\
            const unsigned d1 = (unsigned)((cv) - c1);                         \
            if (d1 < CBLK) { int s = atomicAdd(&cnt[1], 1);                    \
                             if (s < CAP) lst[1][s] = ((idx) << 5) | (int)d1; }}
        DM_CHK(v.x, ii + 0)
        DM_CHK(v.y, ii + 1)
        DM_CHK(v.z, ii + 2)
        DM_CHK(v.w, ii + 3)
#undef DM_CHK
    }

    // --- tile-0 regs -> LDS (transposed) ---
#pragma unroll
    for (int rb = 0; rb < 8; ++rb) {
        const int t = rb * 32 + row;
        tile[c4 * 4 + 0][t] = t0r[rb].x;
        tile[c4 * 4 + 1][t] = t0r[rb].y;
        tile[c4 * 4 + 2][t] = t0r[rb].z;
        tile[c4 * 4 + 3][t] = t0r[rb].w;
    }
    __syncthreads();

    // --- prefetch tile-1 into registers (overlaps tile-0 pair phase) ---
    float4 t1r[8];
    if (n1 > 0 && c4 * 4 < n1) {             // partial tile: n1 multiple of 4
#pragma unroll
        for (int rb = 0; rb < 8; ++rb)
            t1r[rb] = *reinterpret_cast<const float4*>(
                &O[(size_t)(rb * 32 + row) * NWORDS + c1 + c4 * 4]);
    }

    const int wave = tid >> 6;
    const int lane = tid & 63;
    const float4* __restrict__ D4 = reinterpret_cast<const float4*>(D);
    const float4* __restrict__ W4 = reinterpret_cast<const float4*>(W);

    // --- pair phase, tile 0 ---
    {
        int n = cnt[0]; if (n > CAP) n = CAP;
        for (int p = wave; p < n; p += 4) {
            const int packed = __builtin_amdgcn_readfirstlane(lst[0][p]);
            const int i = packed >> 5;
            const int c = packed & (CBLK - 1);
            const unsigned b = (unsigned)i / NK;
            const int dc = doc[b];
            const int* __restrict__ cb = &ctx[b * NCTX];
            float4 xv = D4[(size_t)dc * 64 + lane];
#pragma unroll
            for (int q = 0; q < NCTX; ++q) {
                const float4 w = W4[(size_t)cb[q] * 64 + lane];
                xv.x += w.x; xv.y += w.y; xv.z += w.z; xv.w += w.w;
            }
            const float4 ov = *reinterpret_cast<const float4*>(&tile[c][lane * 4]);
            float d = xv.x * ov.x + xv.y * ov.y + xv.z * ov.z + xv.w * ov.w;
#pragma unroll
            for (int off = 32; off >= 1; off >>= 1)
                d += __shfl_down(d, off, 64);
            if (lane == 0) out[i] = d;
        }
    }
    __syncthreads();

    // --- tile-1 regs -> LDS ---
    if (n1 > 0 && c4 * 4 < n1) {
#pragma unroll
        for (int rb = 0; rb < 8; ++rb) {
            const int t = rb * 32 + row;
            tile[c4 * 4 + 0][t] = t1r[rb].x;
            tile[c4 * 4 + 1][t] = t1r[rb].y;
            tile[c4 * 4 + 2][t] = t1r[rb].z;
            tile[c4 * 4 + 3][t] = t1r[rb].w;
        }
    }
    __syncthreads();

    // --- pair phase, tile 1 ---
    {
        int n = cnt[1]; if (n > CAP) n = CAP;
        for (int p = wave; p < n; p += 4) {
            const int packed = __builtin_amdgcn_readfirstlane(lst[1][p]);
            const int i = packed >> 5;
            const int c = packed & (CBLK - 1);
            const unsigned b = (unsigned)i / NK;
            const int dc = doc[b];
            const int* __restrict__ cb = &ctx[b * NCTX];
            float4 xv = D4[(size_t)dc * 64 + lane];
#pragma unroll
            for (int q = 0; q < NCTX; ++q) {
                const float4 w = W4[(size_t)cb[q] * 64 + lane];
                xv.x += w.x; xv.y += w.y; xv.z += w.z; xv.w += w.w;
            }
            const float4 ov = *reinterpret_cast<const float4*>(&tile[c][lane * 4]);
            float d = xv.x * ov.x + xv.y * ov.y + xv.z * ov.z + xv.w * ov.w;
#pragma unroll
            for (int off = 32; off >= 1; off >>= 1)
                d += __shfl_down(d, off, 64);
            if (lane == 0) out[i] = d;
        }
    }
}

extern "C" void kernel_launch(void* const* d_in, const int* in_sizes, int n_in,
                              void* d_out, int out_size, void* d_ws, size_t ws_size,
                              hipStream_t stream)
{
    const int*   ctx = (const int*)d_in[0];   // (4096, 8)
    const int*   doc = (const int*)d_in[1];   // (4096,)
    const int*   tgt = (const int*)d_in[2];   // (4096, 6)
    const float* D   = (const float*)d_in[3]; // (100000, 256)
    const float* W   = (const float*)d_in[4]; // (50000, 256)
    const float* O   = (const float*)d_in[5]; // (256, 50000)
    float*       out = (float*)d_out;         // (4096, 6)

    DM_42417097016803_fused<<<GRID, 256, 0, stream>>>(ctx, doc, tgt, D, W, O, out);
}

// Round 6
// 35.904 us; speedup vs baseline: 1.6428x; 1.6428x over previous
//
#include <hip/hip_runtime.h>

#define BATCH     4096
#define NCTX      8
#define NK        6
#define VDIM      256
#define NWORDS    50000
#define NPAIRS    (BATCH * NK)              // 24576
#define CBLK      32                        // columns of O per score block
#define NBINS     ((NWORDS + CBLK - 1) / CBLK)   // 1563
#define CAP       64                        // pairs per bin (mean 15.7; ~10 sigma headroom)
#define TSTRIDE   (VDIM + 2)                // 258: write-side 2-way (free), read contiguous

#define X_ELEMS   (BATCH * VDIM)

// ---------------------------------------------------------------------------
// Kernel 1: x[b,:] = D[doc[b],:] + sum_c W[ctx[b,c],:]  -> ws. One wave per
// batch element, float4/lane. Block 0 also zeroes bin counters (stream order
// makes them visible to kernel 2).
// ---------------------------------------------------------------------------
__global__ __launch_bounds__(256)
void DM_42417097016803_xbuild(const int* __restrict__ ctx,
                              const int* __restrict__ doc,
                              const float* __restrict__ D,
                              const float* __restrict__ W,
                              float* __restrict__ x,
                              int* __restrict__ counts)
{
    if (blockIdx.x == 0) {
        for (int j = threadIdx.x; j < NBINS; j += 256) counts[j] = 0;
    }

    const int wave = threadIdx.x >> 6;
    const int lane = threadIdx.x & 63;
    const int b    = blockIdx.x * 4 + wave;

    const float4* __restrict__ D4 = reinterpret_cast<const float4*>(D);
    const float4* __restrict__ W4 = reinterpret_cast<const float4*>(W);
    float4* __restrict__       x4 = reinterpret_cast<float4*>(x);

    const int docid = doc[b];
    float4 v = D4[(size_t)docid * 64 + lane];
#pragma unroll
    for (int c = 0; c < NCTX; ++c) {
        const int id = ctx[b * NCTX + c];
        const float4 w = W4[(size_t)id * 64 + lane];
        v.x += w.x; v.y += w.y; v.z += w.z; v.w += w.w;
    }
    x4[(size_t)b * 64 + lane] = v;
}

// ---------------------------------------------------------------------------
// Kernel 2: bin the 24576 (b,k) pairs by column-block of their target id.
// Stores packed (pair_idx << 5) | (col & 31).
// ---------------------------------------------------------------------------
__global__ __launch_bounds__(256)
void DM_42417097016803_bin(const int* __restrict__ tgt,
                           int* __restrict__ counts,
                           int* __restrict__ bins)
{
    const int i = blockIdx.x * 256 + threadIdx.x;   // exactly NPAIRS threads
    const int c = tgt[i];
    const int bin = c >> 5;                          // CBLK = 32
    const int pos = atomicAdd(&counts[bin], 1);
    if (pos < CAP) bins[bin * CAP + pos] = (i << 5) | (c & (CBLK - 1));
}

// ---------------------------------------------------------------------------
// Kernel 3: block bid owns O columns [bid*32, bid*32+32). Stream the 256x32
// tile into LDS transposed (O read exactly once chip-wide, coalesced), then
// waves process binned pairs in chunks of 4: issue 4 independent x-loads +
// 4 LDS column reads, THEN do the 4 dot/reduce chains (latency hidden 4x).
// ---------------------------------------------------------------------------
__global__ __launch_bounds__(256, 4)
void DM_42417097016803_score(const int* __restrict__ counts,
                             const int* __restrict__ bins,
                             const float* __restrict__ x,
                             const float* __restrict__ O,
                             float* __restrict__ out)
{
    __shared__ float tile[CBLK][TSTRIDE];   // 33 KB

    const int tid = threadIdx.x;
    const int bid = blockIdx.x;
    const int c0  = bid * CBLK;
    const int ncols = (NWORDS - c0 < CBLK) ? (NWORDS - c0) : CBLK;

    const int c4  = tid & 7;        // float4-column within tile
    const int row = tid >> 3;       // 0..31
    const bool ld = (c4 * 4 < ncols);   // last block: ncols=16 (mult of 4)

    // issue all 8 global tile loads first (in flight during setup)
    float4 r[8];
    if (ld) {
#pragma unroll
        for (int rb = 0; rb < 8; ++rb)
            r[rb] = *reinterpret_cast<const float4*>(
                &O[(size_t)(rb * 32 + row) * NWORDS + c0 + c4 * 4]);
    }

    int np = counts[bid];
    if (np > CAP) np = CAP;

    if (ld) {
#pragma unroll
        for (int rb = 0; rb < 8; ++rb) {
            const int t = rb * 32 + row;
            tile[c4 * 4 + 0][t] = r[rb].x;
            tile[c4 * 4 + 1][t] = r[rb].y;
            tile[c4 * 4 + 2][t] = r[rb].z;
            tile[c4 * 4 + 3][t] = r[rb].w;
        }
    }
    __syncthreads();

    const int wave = tid >> 6;
    const int lane = tid & 63;
    const float4* __restrict__ x4 = reinterpret_cast<const float4*>(x);

    // chunk of up to 4 pairs per wave per iteration
    for (int base = wave; base < np; base += 16) {
        int    idx[4];
        float4 xv[4], ov[4];
        int m = 0;
#pragma unroll
        for (int j = 0; j < 4; ++j) {
            const int p = base + j * 4;
            if (p < np) {
                const int packed = bins[bid * CAP + p];
                const int i = packed >> 5;
                const int c = packed & (CBLK - 1);
                idx[j] = i;
                xv[j]  = x4[(size_t)((unsigned)i / NK) * 64 + lane];
                ov[j]  = *reinterpret_cast<const float4*>(&tile[c][lane * 4]);
                m = j + 1;
            }
        }
#pragma unroll
        for (int j = 0; j < 4; ++j) {
            if (j < m) {
                float d = xv[j].x * ov[j].x + xv[j].y * ov[j].y
                        + xv[j].z * ov[j].z + xv[j].w * ov[j].w;
#pragma unroll
                for (int off = 32; off >= 1; off >>= 1)
                    d += __shfl_down(d, off, 64);
                if (lane == 0) out[idx[j]] = d;
            }
        }
    }
}

// ---------------------------------------------------------------------------
// Fallback (direct strided-O gather) in case ws is too small.
// ---------------------------------------------------------------------------
__global__ __launch_bounds__(256)
void DM_42417097016803_fallback(const int* __restrict__ ctx,
                                const int* __restrict__ doc,
                                const int* __restrict__ tid,
                                const float* __restrict__ D,
                                const float* __restrict__ W,
                                const float* __restrict__ O,
                                float* __restrict__ out)
{
    const int b = blockIdx.x;
    const int t = threadIdx.x;

    __shared__ int s_idx[NCTX + NK + 1];
    if (t < NCTX)            s_idx[t] = ctx[b * NCTX + t];
    else if (t < NCTX + NK)  s_idx[t] = tid[b * NK + (t - NCTX)];
    else if (t == NCTX + NK) s_idx[t] = doc[b];
    __syncthreads();

    const int docid = s_idx[NCTX + NK];
    float x = D[(size_t)docid * VDIM + t];
#pragma unroll
    for (int c = 0; c < NCTX; ++c)
        x += W[(size_t)s_idx[c] * VDIM + t];

    float p[NK];
#pragma unroll
    for (int k = 0; k < NK; ++k)
        p[k] = x * O[(size_t)t * NWORDS + s_idx[NCTX + k]];

#pragma unroll
    for (int k = 0; k < NK; ++k) {
#pragma unroll
        for (int off = 32; off >= 1; off >>= 1)
            p[k] += __shfl_down(p[k], off, 64);
    }

    __shared__ float s_part[4][NK];
    const int wave = t >> 6;
    const int lane = t & 63;
    if (lane == 0) {
#pragma unroll
        for (int k = 0; k < NK; ++k) s_part[wave][k] = p[k];
    }
    __syncthreads();

    if (t < NK)
        out[b * NK + t] = s_part[0][t] + s_part[1][t] + s_part[2][t] + s_part[3][t];
}

extern "C" void kernel_launch(void* const* d_in, const int* in_sizes, int n_in,
                              void* d_out, int out_size, void* d_ws, size_t ws_size,
                              hipStream_t stream)
{
    const int*   ctx = (const int*)d_in[0];   // (4096, 8)
    const int*   doc = (const int*)d_in[1];   // (4096,)
    const int*   tid = (const int*)d_in[2];   // (4096, 6)
    const float* D   = (const float*)d_in[3]; // (100000, 256)
    const float* W   = (const float*)d_in[4]; // (50000, 256)
    const float* O   = (const float*)d_in[5]; // (256, 50000)
    float*       out = (float*)d_out;         // (4096, 6)

    const size_t x_bytes     = (size_t)X_ELEMS * sizeof(float);       // 4 MB
    const size_t count_bytes = (size_t)NBINS * sizeof(int);
    const size_t bin_bytes   = (size_t)NBINS * CAP * sizeof(int);

    if (ws_size >= x_bytes + count_bytes + bin_bytes) {
        float* x      = (float*)d_ws;
        int*   counts = (int*)((char*)d_ws + x_bytes);
        int*   bins   = counts + NBINS;

        DM_42417097016803_xbuild<<<BATCH / 4, 256, 0, stream>>>(
            ctx, doc, D, W, x, counts);
        DM_42417097016803_bin<<<NPAIRS / 256, 256, 0, stream>>>(
            tid, counts, bins);
        DM_42417097016803_score<<<NBINS, 256, 0, stream>>>(
            counts, bins, x, O, out);
    } else {
        DM_42417097016803_fallback<<<BATCH, 256, 0, stream>>>(
            ctx, doc, tid, D, W, O, out);
    }
}